// Round 17
// baseline (695.598 us; speedup 1.0000x reference)
//
#include <hip/hip_runtime.h>
#include <hip/hip_bf16.h>
#include <math.h>

#define V_  50257
#define D_  512
#define H_  8
#define NL_ 4
#define C_  10
#define CD_ 64
#define B_  16
#define L_  512
#define DH_ 64

typedef __attribute__((ext_vector_type(8))) short bf16x8;
typedef __attribute__((ext_vector_type(4))) float f32x4;

__device__ inline float bf2f(unsigned short u) {
    union { unsigned int i; float f; } c; c.i = ((unsigned int)u) << 16; return c.f;
}
__device__ inline unsigned short f2bf(float f) {
    unsigned int x = __float_as_uint(f);
    unsigned int r = (x + 0x7fffu + ((x >> 16) & 1u)) >> 16;
    return (unsigned short)r;
}
__device__ inline unsigned long long pack4(float a, float b, float c, float d) {
    return (unsigned long long)f2bf(a)         |
           ((unsigned long long)f2bf(b) << 16) |
           ((unsigned long long)f2bf(c) << 32) |
           ((unsigned long long)f2bf(d) << 48);
}

// async global->LDS, 16B per lane. LDS dest is wave-uniform base + lane*16
// (HW rule); global src is per-lane => swizzled layouts are achieved by
// pre-permuting the SOURCE address with the same involution used on reads.
__device__ inline void gload16(const unsigned short* g, unsigned short* l) {
    __builtin_amdgcn_global_load_lds(
        (const __attribute__((address_space(1))) unsigned int*)g,
        (__attribute__((address_space(3))) unsigned int*)l,
        16, 0, 0);
}

// ---------------------------------------------------------------------------
// bf16 MFMA GEMM: C = epi(A @ B^T + bias [+ res]).  A:(M,K) B:(N,K) row-major.
// 2-phase double-buffered schedule, BK=64: tile t+1's async global_load_lds
// issued BEFORE tile t's ds_read+MFMA; ONE __syncthreads per 64-wide K-step.
// LDS rows 64 shorts (128B) = 8 x 16B slots; XOR swizzle slot ^= row&7
// (2-way = free), applied to read slot AND pre-swizzled gload16 source.
// Dynamic LDS: 64KB (128x128) / 48KB (64x128) -> 2 blocks/CU.
// Tiles: 128x128 big-N; 64x128 for N=512 (512 blocks=2/CU). 128x256
// REGRESSED (r12 occupancy cliff); BK=128 rejected (m132).
// MFMA frag maps (16x16x32): A/B lane l -> row l&15, k (l>>4)*8+j;
//                            C/D lane l -> col l&15, row (l>>4)*4+r.
// EPI: 0 = bf16 out (+bias), 2 = bf16 gelu(+bias),
//      3 = bf16 out (+bias + bf16 res)  [pre-LN sum],
//      4 = qkv: cols<1024 like EPI0; V-col blocks (rowB0>=1024, uniform)
//          transpose acc through padded LDS and store vt (r16, verified).
// ---------------------------------------------------------------------------
template<int BM, int BN, int WGM, int WGN, int EPI>
__global__ __launch_bounds__(256) void gemm_bf16(
    const unsigned short* __restrict__ A, int lda, long aHi, long aLo,
    const unsigned short* __restrict__ B, int ldb, long bHi, long bLo,
    void* __restrict__ Cout, int ldc, long cHi, long cLo,
    const float* __restrict__ bias,
    const unsigned short* __restrict__ resb, int ldr,
    int K, unsigned short* __restrict__ vtout)
{
    constexpr int BK = 64;
    constexpr int FM = BM / (WGM * 16);
    constexpr int FN = BN / (WGN * 16);
    constexpr int CHA = BM / 8;         // 1KB chunks (8 rows x 128B) in A tile
    constexpr int CHB = BN / 8;
    extern __shared__ unsigned short glds[];
    unsigned short* As = glds;                  // [2][BM*BK]
    unsigned short* Bs = glds + 2 * BM * BK;    // [2][BN*BK]

    const int z  = blockIdx.z;
    const int zh = z >> 3, zl = z & 7;
    A += zh * aHi + zl * aLo;
    B += zh * bHi + zl * bLo;
    const long coff = zh * cHi + zl * cLo;

    const int tid  = threadIdx.x;
    const int lane = tid & 63;
    const int w    = tid >> 6;
    const int wr   = w / WGN, wc = w % WGN;
    const long rowA0 = (long)blockIdx.x * BM;
    const long rowB0 = (long)blockIdx.y * BN;

    f32x4 acc[FM][FN];
    #pragma unroll
    for (int m = 0; m < FM; m++)
        #pragma unroll
        for (int n = 0; n < FN; n++)
            #pragma unroll
            for (int r = 0; r < 4; r++) acc[m][n][r] = 0.f;

    const int lr   = lane & 15;
    const int crow = lane >> 3;                        // row within 8-row chunk
    const int ccol = ((lane & 7) ^ crow) * 8;          // pre-swizzled src col

    auto stage = [&](int bf, int k0) {
        #pragma unroll
        for (int c0 = 0; c0 < CHA / 4; c0++) {
            const int c = c0 * 4 + w;
            gload16(&A[(rowA0 + c * 8 + crow) * (long)lda + k0 + ccol],
                    &As[bf * BM * BK + c * 512]);
        }
        #pragma unroll
        for (int c0 = 0; c0 < CHB / 4; c0++) {
            const int c = c0 * 4 + w;
            gload16(&B[(rowB0 + c * 8 + crow) * (long)ldb + k0 + ccol],
                    &Bs[bf * BN * BK + c * 512]);
        }
    };

    stage(0, 0);
    int cur = 0;
    for (int k0 = 0; k0 < K; k0 += BK) {
        __syncthreads();   // tile t landed (vmcnt0); prev readers of cur^1 done
        if (k0 + BK < K) stage(cur ^ 1, k0 + BK);   // prefetch next tile

        #pragma unroll
        for (int kh = 0; kh < 2; kh++) {
            bf16x8 af[FM], bfr[FN];
            const int sl = ((kh * 4 + (lane >> 4)) ^ (lr & 7)) * 8;
            #pragma unroll
            for (int m = 0; m < FM; m++)
                af[m] = *(const bf16x8*)
                    &As[cur * BM * BK + (wr * FM * 16 + m * 16 + lr) * BK + sl];
            #pragma unroll
            for (int n = 0; n < FN; n++)
                bfr[n] = *(const bf16x8*)
                    &Bs[cur * BN * BK + (wc * FN * 16 + n * 16 + lr) * BK + sl];
            #pragma unroll
            for (int m = 0; m < FM; m++)
                #pragma unroll
                for (int n = 0; n < FN; n++)
                    acc[m][n] = __builtin_amdgcn_mfma_f32_16x16x32_bf16(
                        af[m], bfr[n], acc[m][n], 0, 0, 0);
        }
        cur ^= 1;
    }

    const int rg = (lane >> 4) * 4;
    if constexpr (EPI == 4) {
        if (rowB0 >= 2 * D_) {
            // ---- V-col block: acc -> LDS (padded) -> transposed vt store ----
            unsigned short* T = glds;          // [128 rows l][stride 132] bf16
            __syncthreads();                   // all K-loop LDS reads done
            #pragma unroll
            for (int m = 0; m < FM; m++)
                #pragma unroll
                for (int n = 0; n < FN; n++) {
                    const int lcol = wc * FN * 16 + n * 16 + lr;     // 0..127
                    const float bv = bias[(int)rowB0 + lcol];
                    #pragma unroll
                    for (int r = 0; r < 4; r++) {
                        const int lrow = wr * FM * 16 + m * 16 + rg + r;
                        T[lrow * 132 + lcol] = f2bf(acc[m][n][r] + bv);
                    }
                }
            __syncthreads();
            const int bb = (int)(rowA0 >> 9);          // batch (BM=128 | 512)
            const int l0 = (int)(rowA0 & 511);         // l-tile base (128-al)
            const int vcBase = (int)(rowB0 - 2 * D_);  // 0..384 step 128
            for (int c = tid; c < 2048; c += 256) {
                const int vc    = c & 127;             // local v col
                const int ch    = c >> 7;              // 0..15 l-chunk of 8
                const int lt2   = ch >> 3;             // 64-l tile (0/1)
                const int gslot = ch & 7;
                const int gvc = vcBase + vc;
                const int hd = gvc >> 6, d = gvc & 63;
                bf16x8 o;
                #pragma unroll
                for (int j = 0; j < 8; j++)
                    o[j] = (short)T[(lt2 * 64 + gslot * 8 + j) * 132 + vc];
                *(bf16x8*)&vtout[(long)(bb * 8 + hd) * (DH_ * L_)
                                 + (long)d * 512 + l0 + lt2 * 64
                                 + ((gslot ^ (d & 7)) * 8)] = o;
            }
            return;
        }
        // Q,K cols: plain bf16 store to qkv
        #pragma unroll
        for (int m = 0; m < FM; m++)
            #pragma unroll
            for (int n = 0; n < FN; n++) {
                const int col = (int)rowB0 + wc * FN * 16 + n * 16 + lr;
                const float bv = bias[col];
                #pragma unroll
                for (int r = 0; r < 4; r++) {
                    const long row = rowA0 + wr * FM * 16 + m * 16 + rg + r;
                    ((unsigned short*)Cout)[row * ldc + col] =
                        f2bf(acc[m][n][r] + bv);
                }
            }
        return;
    }

    #pragma unroll
    for (int m = 0; m < FM; m++) {
        #pragma unroll
        for (int n = 0; n < FN; n++) {
            const int col = (int)rowB0 + wc * FN * 16 + n * 16 + lr;
            const float bv = bias ? bias[col] : 0.f;
            #pragma unroll
            for (int r = 0; r < 4; r++) {
                const long row = rowA0 + wr * FM * 16 + m * 16 + rg + r;
                float v = acc[m][n][r] + bv;
                const long o = coff + row * ldc + col;
                if constexpr (EPI == 0) {
                    ((unsigned short*)Cout)[o] = f2bf(v);
                } else if constexpr (EPI == 3) {
                    ((unsigned short*)Cout)[o] =
                        f2bf(v + bf2f(resb[row * ldr + col]));
                } else {
                    float g = 0.5f * v * (1.f + erff(v * 0.70710678118f));
                    ((unsigned short*)Cout)[o] = f2bf(g);
                }
            }
        }
    }
}

// ---------------------------------------------------------------------------
// Fused attention v4: QK^T fragment-reuse repartition.
// One block = 64 q-rows of one (b,h). QK^T as mfma(K,Q), but wave w now owns
// ALL 64 q (4 Q-frags) x keys [w*128, w*128+128) (8 K-tiles): per slice
// 4 Q + 8 K ds_reads feed 32 MFMA (2.7 MFMA/read vs 1.0 in v3 — QK^T was
// LDS-feed-bound: 66 reads for 64 MFMA). acc[qf][n][r]: q = qf*16+lr,
// k = w*128 + n*16 + lg*4 + r.
// Softmax: in-lane tree over the wave's 128 keys + shfl(16,32), then
// cross-wave combine via redM/redS[4][64] (alias dead Qs; +2 barriers).
// P~ = exp(S-gmax), un-normalized; rinv folded into O store.
// PV per 256-key half: waves owning that half (w>>1 == hf) write P~ packed
// 4-wide into swizzled Ps; V^T staged via LINEAR gload16 from pre-swizzled
// vt into Vb; wave w computes d-tile w for ALL 64 q: accO[qt].
// All LDS rows keep the slot ^= (lr&7) involution -> 2-way banks (free).
// LDS 72KB -> 2 blocks/CU. Grid 1-D, head = bid&127 (XCD L2 reuse).
// ---------------------------------------------------------------------------
__global__ __launch_bounds__(256) void attn_kernel(
    const unsigned short* __restrict__ qkv,   // (B, L, 3D) bf16 (Q,K valid)
    const unsigned short* __restrict__ vt,    // (B*H, 64, 512) bf16 V^T, swz
    unsigned short* __restrict__ attno)       // (B, L, D) bf16
{
    extern __shared__ unsigned short lds[];   // 36864 shorts = 72KB
    unsigned short* Qs = lds;                 // [64][64]   swz ^row&7
    unsigned short* Ks = lds + 4096;          // [512][64]  swz ^row&7
    unsigned short* Ps = lds + 4096;          // [64 q][256] per-half (alias)
    unsigned short* Vb = lds + 20480;         // [64 d][256] swz ^(d&7) (alias)
    float* redM = (float*)lds;                // [4][64] max (aliases dead Qs)
    float* redS = (float*)lds + 256;          // [4][64] sum

    const int bid = blockIdx.x;
    const int z   = bid & 127;                // b*8+h
    const int qb  = bid >> 7;
    const int b = z >> 3, hh = z & 7;
    const unsigned short* Q  = qkv + (long)b * (L_ * 3 * D_) + hh * DH_;
    const unsigned short* Kp = Q + D_;
    const int row0 = qb * 64;

    const int tid = threadIdx.x, lane = tid & 63, w = tid >> 6;
    const int lr = lane & 15, lg = lane >> 4;

    // ---- stage Q (8 chunks) + K (64 chunks); 1KB chunk = 8 rows x 128B ----
    const int srow = lane >> 3;
    const int scol = ((lane & 7) ^ (srow & 7)) * 8;   // pre-swizzled src col
    #pragma unroll
    for (int c = 0; c < 2; c++)
        gload16(&Q[(long)(row0 + (w * 2 + c) * 8 + srow) * (3 * D_) + scol],
                &Qs[(w * 2 + c) * 512]);
    #pragma unroll
    for (int c = 0; c < 16; c++)
        gload16(&Kp[(long)((c * 4 + w) * 8 + srow) * (3 * D_) + scol],
                &Ks[(c * 4 + w) * 512]);
    __syncthreads();

    // ---- QK^T: acc[qf][n][r] = S[k = w*128+n*16+lg*4+r][q = qf*16+lr] ----
    f32x4 acc[4][8];
    #pragma unroll
    for (int qf = 0; qf < 4; qf++)
        #pragma unroll
        for (int n = 0; n < 8; n++)
            #pragma unroll
            for (int r = 0; r < 4; r++) acc[qf][n][r] = 0.f;

    __builtin_amdgcn_s_setprio(1);
    #pragma unroll
    for (int ks = 0; ks < 2; ks++) {
        const int sl = ((ks * 4 + lg) ^ (lr & 7)) * 8;
        bf16x8 qfv[4];
        #pragma unroll
        for (int qf = 0; qf < 4; qf++)
            qfv[qf] = *(const bf16x8*)&Qs[(qf * 16 + lr) * 64 + sl];
        #pragma unroll
        for (int n = 0; n < 8; n++) {
            bf16x8 kf = *(const bf16x8*)&Ks[(w * 128 + n * 16 + lr) * 64 + sl];
            #pragma unroll
            for (int qf = 0; qf < 4; qf++)
                acc[qf][n] = __builtin_amdgcn_mfma_f32_16x16x32_bf16(
                    kf, qfv[qf], acc[qf][n], 0, 0, 0);
        }
    }
    __builtin_amdgcn_s_setprio(0);

    // ---- softmax: local (wave's 128 keys) then cross-wave combine ----
    constexpr float scale = 0.125f;           // 1/sqrt(64)
    float rmax[4];
    #pragma unroll
    for (int qf = 0; qf < 4; qf++) {
        float t = -3e38f;
        #pragma unroll
        for (int n = 0; n < 8; n++)
            t = fmaxf(t, fmaxf(fmaxf(acc[qf][n][0], acc[qf][n][1]),
                               fmaxf(acc[qf][n][2], acc[qf][n][3])));
        t = fmaxf(t, __shfl_xor(t, 16));
        t = fmaxf(t, __shfl_xor(t, 32));
        rmax[qf] = t;
    }
    __syncthreads();   // A: all QK^T Qs/Ks reads done -> redM writable
    if (lg == 0) {
        #pragma unroll
        for (int qf = 0; qf < 4; qf++)
            redM[w * 64 + qf * 16 + lr] = rmax[qf];
    }
    __syncthreads();   // B
    float gms[4];
    #pragma unroll
    for (int qf = 0; qf < 4; qf++) {
        const int q = qf * 16 + lr;
        gms[qf] = fmaxf(fmaxf(redM[q], redM[64 + q]),
                        fmaxf(redM[128 + q], redM[192 + q])) * scale;
    }
    float rsum[4];
    #pragma unroll
    for (int qf = 0; qf < 4; qf++) {
        float s = 0.f;
        #pragma unroll
        for (int n = 0; n < 8; n++) {
            float e0 = __expf(acc[qf][n][0] * scale - gms[qf]);
            float e1 = __expf(acc[qf][n][1] * scale - gms[qf]);
            float e2 = __expf(acc[qf][n][2] * scale - gms[qf]);
            float e3 = __expf(acc[qf][n][3] * scale - gms[qf]);
            acc[qf][n][0] = e0; acc[qf][n][1] = e1;
            acc[qf][n][2] = e2; acc[qf][n][3] = e3;
            s += (e0 + e1) + (e2 + e3);
        }
        s += __shfl_xor(s, 16);
        s += __shfl_xor(s, 32);
        rsum[qf] = s;
    }
    if (lg == 0) {
        #pragma unroll
        for (int qf = 0; qf < 4; qf++)
            redS[w * 64 + qf * 16 + lr] = rsum[qf];
    }
    __syncthreads();   // C: sums visible; Ks fully dead -> Ps writable
    float rinv[4];
    #pragma unroll
    for (int qf = 0; qf < 4; qf++) {
        const int q = qf * 16 + lr;
        rinv[qf] = 1.f / (redS[q] + redS[64 + q] + redS[128 + q] + redS[192 + q]);
    }

    // ---- PV in two 256-key halves; wave w owns d-tile w for all 64 q ----
    const long vbase = (long)z * (DH_ * L_);
    const int vrow2 = lane >> 5;              // V chunk = 2 rows x 512B
    const int vs    = lane & 31;
    const int myhalf = w >> 1;
    const int rawbase = (w & 1) * 16;         // klocal>>3 base within my half
    f32x4 accO[4];
    #pragma unroll
    for (int qt = 0; qt < 4; qt++)
        #pragma unroll
        for (int r = 0; r < 4; r++) accO[qt][r] = 0.f;

    #pragma unroll
    for (int hf = 0; hf < 2; hf++) {
        if (hf) __syncthreads();   // PV h0 Ps/Vb reads done before overwrite
        // issue V-half stage first (linear copy; swizzle pre-baked in vt)
        #pragma unroll
        for (int c = 0; c < 8; c++) {
            const int ch = c * 4 + w;
            const int dloc = ch * 2 + vrow2;
            gload16(&vt[vbase + (long)dloc * 512 + hf * 256 + vs * 8],
                    &Vb[ch * 512]);
        }
        // waves owning this key-half write P~ (32 x ds_write_b64 each)
        if (myhalf == hf) {
            #pragma unroll
            for (int qf = 0; qf < 4; qf++) {
                const int q = qf * 16 + lr;
                #pragma unroll
                for (int n = 0; n < 8; n++) {
                    const int slot = (rawbase + n * 2 + (lg >> 1)) ^ (lr & 7);
                    unsigned long long pk = pack4(
                        acc[qf][n][0], acc[qf][n][1],
                        acc[qf][n][2], acc[qf][n][3]);
                    *(unsigned long long*)&Ps[q * 256 + slot * 8 + (lg & 1) * 4] = pk;
                }
            }
        }
        __syncthreads();           // Vb landed (vmcnt0) + Ps visible
        __builtin_amdgcn_s_setprio(1);
        #pragma unroll
        for (int kstep = 0; kstep < 8; kstep++) {
            const int sl = ((kstep * 4 + lg) ^ (lr & 7)) * 8;
            bf16x8 vf = *(const bf16x8*)&Vb[(w * 16 + lr) * 256 + sl];
            #pragma unroll
            for (int qt = 0; qt < 4; qt++) {
                bf16x8 pf = *(const bf16x8*)&Ps[(qt * 16 + lr) * 256 + sl];
                accO[qt] = __builtin_amdgcn_mfma_f32_16x16x32_bf16(
                    vf, pf, accO[qt], 0, 0, 0);
            }
        }
        __builtin_amdgcn_s_setprio(0);
    }

    // ---- store O: q = qt*16+lr, d = w*16 + lg*4 + r, packed 8B ----
    unsigned short* op = attno + (long)(b * L_ + row0) * D_ + hh * DH_;
    #pragma unroll
    for (int qt = 0; qt < 4; qt++) {
        unsigned long long pk = pack4(accO[qt][0] * rinv[qt], accO[qt][1] * rinv[qt],
                                      accO[qt][2] * rinv[qt], accO[qt][3] * rinv[qt]);
        *(unsigned long long*)&op[(long)(qt * 16 + lr) * D_ + w * 16 + lg * 4] = pk;
    }
}

// ---------------------------------------------------------------------------
// All four weight tensors -> bf16 arena in one launch (regions contiguous).
__global__ __launch_bounds__(256) void cvtall_kernel(
    const float* __restrict__ s0, const float* __restrict__ s1,
    const float* __restrict__ s2, const float* __restrict__ s3,
    unsigned short* __restrict__ dst)
{
    const long n0 = 786432, n1 = 262144, n2 = 1048576;   // float4 counts
    long i4 = (long)blockIdx.x * 256 + threadIdx.x;
    const float* s; long off;
    if (i4 < n0)                { s = s0; off = 0; }
    else if (i4 < n0 + n1)      { s = s1; off = n0; }
    else if (i4 < n0 + n1 + n2) { s = s2; off = n0 + n1; }
    else                        { s = s3; off = n0 + n1 + n2; }
    float4 v = ((const float4*)s)[i4 - off];
    *(unsigned long long*)&dst[i4 * 4] = pack4(v.x, v.y, v.z, v.w);
}

__global__ __launch_bounds__(256) void embed_kernel(
    const int* __restrict__ x, const float* __restrict__ emb,
    const float* __restrict__ pos, unsigned short* __restrict__ hb)
{
    const long row = blockIdx.x;            // 0..B*L-1
    const int tok = x[row];
    const int l = (int)(row & (L_ - 1));
    const int d0 = threadIdx.x * 2;
    float2 e = *(const float2*)&emb[(long)tok * D_ + d0];
    float2 p = *(const float2*)&pos[(long)l * D_ + d0];
    float a0 = e.x + p.x, a1 = e.y + p.y;
    unsigned int pk = (unsigned int)f2bf(a0) | ((unsigned int)f2bf(a1) << 16);
    *(unsigned int*)&hb[row * D_ + d0] = pk;
}

// LN over bf16 pre-LN sums (tbuf), writes bf16 hb only (residual stream).
__global__ __launch_bounds__(256) void ln_kernel(
    const unsigned short* __restrict__ t, const float* __restrict__ g,
    const float* __restrict__ bb, unsigned short* __restrict__ hb)
{
    const int lane = threadIdx.x & 63;
    const long row = (long)blockIdx.x * 4 + (threadIdx.x >> 6);
    const unsigned short* x = t + row * D_;
    float v[8];
    bf16x8 d = *(const bf16x8*)&x[lane * 8];
    #pragma unroll
    for (int j = 0; j < 8; j++) v[j] = bf2f((unsigned short)d[j]);
    float s = 0.f;
    #pragma unroll
    for (int j = 0; j < 8; j++) s += v[j];
    #pragma unroll
    for (int o = 32; o; o >>= 1) s += __shfl_xor(s, o);
    const float m = s * (1.f / D_);
    float q = 0.f;
    #pragma unroll
    for (int j = 0; j < 8; j++) { float dd = v[j] - m; q += dd * dd; }
    #pragma unroll
    for (int o = 32; o; o >>= 1) q += __shfl_xor(q, o);
    const float rr = rsqrtf(q * (1.f / D_) + 1e-5f);
    bf16x8 ob;
    #pragma unroll
    for (int j = 0; j < 8; j++) {
        int dd = lane * 8 + j;
        ob[j] = (short)f2bf((v[j] - m) * rr * g[dd] + bb[dd]);
    }
    *(bf16x8*)&hb[row * D_ + lane * 8] = ob;
}

__global__ __launch_bounds__(512) void ctxmean_kernel(
    const unsigned short* __restrict__ hb, float* __restrict__ ctx)
{
    const int b = blockIdx.x, seg = blockIdx.y;
    const int d = threadIdx.x;
    float s = 0.f;
    #pragma unroll 4
    for (int l = seg * 64; l < seg * 64 + 64; l++)
        s += bf2f(hb[((long)b * L_ + l) * D_ + d]);
    atomicAdd(&ctx[b * D_ + d], s * (1.f / L_));
}

__global__ __launch_bounds__(256) void zero_kernel(float* __restrict__ p, long n)
{
    long i = (long)blockIdx.x * 256 + threadIdx.x;
    if (i < n) p[i] = 0.f;
}

// scatter-zero: reset counts only at positions hist will increment.
// duplicate-token write races all write 0.0f -> benign, deterministic.
__global__ __launch_bounds__(256) void zscat_kernel(
    const int* __restrict__ x, float* __restrict__ counts)
{
    const int i = blockIdx.x * 256 + threadIdx.x;
    if (i >= B_ * L_) return;
    const int tok = x[i];
    if (tok != 0) counts[(long)(i >> 9) * V_ + tok] = 0.f;
}

__global__ __launch_bounds__(256) void hist_kernel(
    const int* __restrict__ x, float* __restrict__ counts)
{
    const int i = blockIdx.x * 256 + threadIdx.x;
    if (i >= B_ * L_) return;
    const int tok = x[i];
    if (tok != 0) atomicAdd(&counts[(long)(i >> 9) * V_ + tok], 1.0f);
}

// Σ_v c_v = #nonpad tokens; Σ_v c_v² = Σ_{t,nonpad} c[x_t]  (512 gathers/b
// instead of a 50257-scan; single block per b, no atomics, exact integers).
__global__ __launch_bounds__(512) void cstats_kernel(
    const int* __restrict__ x, const float* __restrict__ counts,
    float* __restrict__ statsraw)
{
    const int b = blockIdx.x, t = threadIdx.x;
    const int tok = x[b * L_ + t];
    float s1 = 0.f, s2 = 0.f;
    if (tok != 0) { s1 = 1.f; s2 = counts[(long)b * V_ + tok]; }
    #pragma unroll
    for (int o = 32; o; o >>= 1) { s1 += __shfl_xor(s1, o); s2 += __shfl_xor(s2, o); }
    __shared__ float r1[8], r2[8];
    if ((t & 63) == 0) { r1[t >> 6] = s1; r2[t >> 6] = s2; }
    __syncthreads();
    if (t == 0) {
        float t1 = 0.f, t2 = 0.f;
        #pragma unroll
        for (int i = 0; i < 8; i++) { t1 += r1[i]; t2 += r2[i]; }
        statsraw[b * 2] = t1;
        statsraw[b * 2 + 1] = t2;
    }
}

// Pure scaled transpose: WcT_g[v][cd] = Wc[cd][v] * g[v]  (no atomics)
__global__ __launch_bounds__(256) void wct_kernel(
    const float* __restrict__ Wc, const float* __restrict__ g,
    float* __restrict__ WcT)
{
    __shared__ float tile[64][65];
    __shared__ float gs[64];
    const int v0 = blockIdx.x * 64;
    const int t = threadIdx.x;
    if (t < 64) gs[t] = (v0 + t < V_) ? g[v0 + t] : 0.f;
    const int vv = t & 63;
    const int vg = v0 + vv;
    #pragma unroll
    for (int r = 0; r < 16; r++) {
        int cd = r * 4 + (t >> 6);
        tile[cd][vv] = (vg < V_) ? Wc[(long)cd * V_ + vg] : 0.f;
    }
    __syncthreads();
    #pragma unroll
    for (int r = 0; r < 16; r++) {
        int v2 = r * 4 + (t >> 6);
        int cd = t & 63;
        if (v0 + v2 < V_)
            WcT[(long)(v0 + v2) * 64 + cd] = tile[cd][v2] * gs[v2];
    }
}

// sgb[cd] = {Σ_v Wc[cd][v]·g[v], Σ_v Wc[cd][v]·β[v]} — 4 chunks/cd, 2 atomics/blk
__global__ __launch_bounds__(256) void sgbred_kernel(
    const float* __restrict__ Wc, const float* __restrict__ g,
    const float* __restrict__ bb, float* __restrict__ sgb)
{
    const int cd = blockIdx.x >> 2, chunk = blockIdx.x & 3;
    const int n0 = chunk * 12565;
    const int n1 = min(n0 + 12565, V_);
    float s1 = 0.f, s2 = 0.f;
    for (int v = n0 + threadIdx.x; v < n1; v += 256) {
        float wv = Wc[(long)cd * V_ + v];
        s1 += wv * g[v];
        s2 += wv * bb[v];
    }
    #pragma unroll
    for (int o = 32; o; o >>= 1) { s1 += __shfl_xor(s1, o); s2 += __shfl_xor(s2, o); }
    __shared__ float r1[4], r2[4];
    if ((threadIdx.x & 63) == 0) { r1[threadIdx.x >> 6] = s1; r2[threadIdx.x >> 6] = s2; }
    __syncthreads();
    if (threadIdx.x == 0) {
        atomicAdd(&sgb[cd * 2],     r1[0] + r1[1] + r1[2] + r1[3]);
        atomicAdd(&sgb[cd * 2 + 1], r2[0] + r2[1] + r2[2] + r2[3]);
    }
}

// dot[b][cd] = Σ_t!=pad WcT_g[x_bt][cd]  (contiguous 256B rows per token)
__global__ __launch_bounds__(256) void cgather_kernel(
    const int* __restrict__ x, const float* __restrict__ WcT,
    float* __restrict__ dot)
{
    const int b = blockIdx.x, seg = blockIdx.y;
    const int wv = threadIdx.x >> 6, lane = threadIdx.x & 63;
    float s = 0.f;
    #pragma unroll
    for (int i = 0; i < 16; i++) {
        int tok = x[b * L_ + seg * 64 + wv * 16 + i];
        if (tok != 0) s += WcT[(long)tok * 64 + lane];
    }
    atomicAdd(&dot[b * 64 + lane], s);
}

__global__ void cfinal_kernel(
    const float* __restrict__ dot, const float* __restrict__ statsraw,
    const float* __restrict__ sgb, const float* __restrict__ bc,
    float* __restrict__ cf)
{
    const int b = blockIdx.x, cd = threadIdx.x;
    const float s1 = statsraw[b * 2], s2 = statsraw[b * 2 + 1];
    const float m = s1 * (1.f / V_);
    const float r = rsqrtf(s2 * (1.f / V_) - m * m + 1e-5f);
    float v = r * (dot[b * 64 + cd] - m * sgb[cd * 2]) + sgb[cd * 2 + 1] + bc[cd];
    cf[b * CD_ + cd] = fmaxf(v, 0.f);
}

__global__ __launch_bounds__(256) void final_kernel(
    const float* __restrict__ ctx, const float* __restrict__ cf,
    const float* __restrict__ Wh, const float* __restrict__ bh,
    float* __restrict__ out)
{
    const int p = threadIdx.x;
    if (p >= B_ * C_) return;
    const int b = p / C_, c = p % C_;
    float s = bh[c];
    const float* wrow = Wh + (long)c * (D_ + CD_);
    for (int d = 0; d < D_; d++) s += ctx[b * D_ + d] * wrow[d];
    for (int j = 0; j < CD_; j++) s += cf[b * CD_ + j] * wrow[D_ + j];
    out[p] = s;
}

// ---------------------------------------------------------------------------
extern "C" void kernel_launch(void* const* d_in, const int* in_sizes, int n_in,
                              void* d_out, int out_size, void* d_ws, size_t ws_size,
                              hipStream_t stream)
{
    const int*   x      = (const int*)  d_in[0];
    const float* embedw = (const float*)d_in[1];
    const float* pos    = (const float*)d_in[2];
    const float* Wqkv   = (const float*)d_in[3];
    const float* bqkv   = (const float*)d_in[4];
    const float* Wo     = (const float*)d_in[5];
    const float* bo     = (const float*)d_in[6];
    const float* ln1g   = (const float*)d_in[7];
    const float* ln1b   = (const float*)d_in[8];
    const float* W1     = (const float*)d_in[9];
    const float* b1     = (const float*)d_in[10];
    const float* W2     = (const float*)d_in[11];
    const float* b2     = (const float*)d_in[12];
    const float* ln2g   = (const float*)d_in[13];
    const float* ln2b   = (const float*)d_in[14];
    const float* cgv    = (const float*)d_in[15];
    const float* cbv    = (const float*)d_in[16];
    const float* Wc     = (const float*)d_in[17];
    const float* bc     = (const float*)d_in[18];
    const float* Wh     = (const float*)d_in[19];
    const float* bh     = (const float*)d_in[20];
    float* out = (float*)d_out;

    char* ws = (char*)d_ws;
    size_t off = 0;
    auto alloc = [&](size_t bytes) -> void* {
        void* p = ws + off;
        off += (bytes + 255) & ~(size_t)255;
        return p;
    };
    unsigned short* hb    = (unsigned short*)alloc((size_t)B_ * L_ * D_ * 2);
    unsigned short* qkv   = (unsigned short*)alloc((size_t)B_ * L_ * 3 * D_ * 2);
    unsigned short* vt    = (unsigned short*)alloc((size_t)B_ * H_ * DH_ * L_ * 2);
    unsigned short* ff1   = (unsigned short*)alloc((size_t)B_ * L_ * 4 * D_ * 2);
    unsigned short* attno = (unsigned short*)alloc((size_t)B_ * L_ * D_ * 2);
    unsigned short* tbuf  = (unsigned short*)alloc((size_t)B_ * L_ * D_ * 2);
    unsigned short* wqb   = (unsigned short*)alloc((size_t)NL_ * 3 * D_ * D_ * 2);
    unsigned short* wob   = (unsigned short*)alloc((size_t)NL_ * D_ * D_ * 2);
    unsigned short* w1b   = (unsigned short*)alloc((size_t)NL_ * 4 * D_ * D_ * 2);
    unsigned short* w2b   = (unsigned short*)alloc((size_t)NL_ * 4 * D_ * D_ * 2);
    float*          counts= (float*)alloc((size_t)B_ * V_ * 4);
    float*          statsraw = (float*)alloc(B_ * 2 * 4);
    float*          sgb   = (float*)alloc(CD_ * 2 * 4);
    float*          dot   = (float*)alloc(B_ * CD_ * 4);
    float*          ctx   = (float*)alloc(B_ * D_ * 4);
    float*          cf    = (float*)alloc(B_ * CD_ * 4);
    // WcT_g (Vpad x 64 f32, 12.9MB) aliases qkv: only used after encoder loop.
    float*          WcT   = (float*)qkv;

    // all weights -> bf16 arena (wqb..w2b contiguous), one launch
    cvtall_kernel<<<12288, 256, 0, stream>>>(Wqkv, Wo, W1, W2, wqb);

    embed_kernel<<<B_*L_, 256, 0, stream>>>(x, embedw, pos, hb);

    // dynamic LDS: (BM+BN)*BK*4 bytes (2 bufs x (A+B) x BK x 2B)
    const int lds_128 = (128 + 128) * 64 * 4;   // 65536
    const int lds_64  = (64 + 128) * 64 * 4;    // 49152

    for (int i = 0; i < NL_; i++) {
        // qkv = h @ Wqkv^T + bqkv  (M=8192,N=1536,K=512); V cols -> vt via
        // LDS-transposed epilogue (vtrans kernel deleted)
        gemm_bf16<128,128,2,2,4><<<dim3(64,12,1),256,lds_128,stream>>>(
            hb, 512, 0, 0,
            wqb + (size_t)i*786432, 512, 0, 0,
            qkv, 1536, 0, 0,
            bqkv + i*1536, nullptr, 0, 512, vt);
        // fused O = softmax(QK^T/8) @ V  (P never leaves the CU)
        attn_kernel<<<1024, 256, 73728, stream>>>(qkv, vt, attno);
        // t = bf16(hb + O @ Wo^T + bo)   (M=8192, N=512, K=512), 512 blocks
        gemm_bf16<64,128,1,4,3><<<dim3(128,4,1),256,lds_64,stream>>>(
            attno, 512, 0, 0,
            wob + (size_t)i*262144, 512, 0, 0,
            tbuf, 512, 0, 0,
            bo + i*512, hb, 512, 512, nullptr);
        ln_kernel<<<2048,256,0,stream>>>(tbuf, ln1g + i*512, ln1b + i*512, hb);
        // ff1 = gelu(h @ W1^T + b1)      (M=8192, N=2048, K=512) -> bf16
        gemm_bf16<128,128,2,2,2><<<dim3(64,16,1),256,lds_128,stream>>>(
            hb, 512, 0, 0,
            w1b + (size_t)i*1048576, 512, 0, 0,
            ff1, 2048, 0, 0,
            b1 + i*2048, nullptr, 0, 512, nullptr);
        // t = bf16(hb + ff1 @ W2^T + b2) (M=8192, N=512, K=2048), 512 blocks
        gemm_bf16<64,128,1,4,3><<<dim3(128,4,1),256,lds_64,stream>>>(
            ff1, 2048, 0, 0,
            w2b + (size_t)i*1048576, 2048, 0, 0,
            tbuf, 512, 0, 0,
            b2 + i*512, hb, 512, 2048, nullptr);
        ln_kernel<<<2048,256,0,stream>>>(tbuf, ln2g + i*512, ln2b + i*512, hb);
    }

    // ---- heads (count path runs after encoder; WcT aliases qkv) ----
    // zero only the atomic-target region (statsraw..cf, ~41KB); counts is
    // scatter-zeroed at exactly the positions hist touches.
    {
        long span = (((char*)cf + ((B_*CD_*4 + 255) & ~255)) - (char*)statsraw) / 4;
        zero_kernel<<<(span + 255)/256, 256, 0, stream>>>(statsraw, span);
    }
    zscat_kernel<<<(B_*L_ + 255)/256, 256, 0, stream>>>(x, counts);
    ctxmean_kernel<<<dim3(B_,8),512,0,stream>>>(hb, ctx);
    hist_kernel<<<(B_*L_ + 255)/256, 256, 0, stream>>>(x, counts);
    cstats_kernel<<<B_,512,0,stream>>>(x, counts, statsraw);
    wct_kernel<<<(V_ + 63)/64, 256, 0, stream>>>(Wc, cgv, WcT);
    sgbred_kernel<<<256,256,0,stream>>>(Wc, cgv, cbv, sgb);
    cgather_kernel<<<dim3(B_,8),256,0,stream>>>(x, WcT, dot);
    cfinal_kernel<<<B_,64,0,stream>>>(dot, statsraw, sgb, bc, cf);
    final_kernel<<<1,256,0,stream>>>(ctx, cf, Wh, bh, out);
}

// Round 18
// 670.659 us; speedup vs baseline: 1.0372x; 1.0372x over previous
//
#include <hip/hip_runtime.h>
#include <hip/hip_bf16.h>
#include <math.h>

#define V_  50257
#define D_  512
#define H_  8
#define NL_ 4
#define C_  10
#define CD_ 64
#define B_  16
#define L_  512
#define DH_ 64

typedef __attribute__((ext_vector_type(8))) short bf16x8;
typedef __attribute__((ext_vector_type(4))) float f32x4;

__device__ inline float bf2f(unsigned short u) {
    union { unsigned int i; float f; } c; c.i = ((unsigned int)u) << 16; return c.f;
}
__device__ inline unsigned short f2bf(float f) {
    unsigned int x = __float_as_uint(f);
    unsigned int r = (x + 0x7fffu + ((x >> 16) & 1u)) >> 16;
    return (unsigned short)r;
}
__device__ inline unsigned long long pack4(float a, float b, float c, float d) {
    return (unsigned long long)f2bf(a)         |
           ((unsigned long long)f2bf(b) << 16) |
           ((unsigned long long)f2bf(c) << 32) |
           ((unsigned long long)f2bf(d) << 48);
}

// async global->LDS, 16B per lane. LDS dest is wave-uniform base + lane*16
// (HW rule); global src is per-lane => swizzled layouts are achieved by
// pre-permuting the SOURCE address with the same involution used on reads.
__device__ inline void gload16(const unsigned short* g, unsigned short* l) {
    __builtin_amdgcn_global_load_lds(
        (const __attribute__((address_space(1))) unsigned int*)g,
        (__attribute__((address_space(3))) unsigned int*)l,
        16, 0, 0);
}

// ---------------------------------------------------------------------------
// bf16 MFMA GEMM: C = epi(A @ B^T + bias [+ res]).  A:(M,K) B:(N,K) row-major.
// 2-phase double-buffered schedule, BK=64: tile t+1's async global_load_lds
// issued BEFORE tile t's ds_read+MFMA; ONE __syncthreads per 64-wide K-step.
// LDS rows 64 shorts (128B) = 8 x 16B slots; XOR swizzle slot ^= row&7
// (2-way = free), applied to read slot AND pre-swizzled gload16 source.
// Dynamic LDS: 64KB (128x128) / 48KB (64x128) -> 2 blocks/CU.
// Tiles: 128x128 big-N; 64x128 for N=512 (512 blocks=2/CU). 128x256
// REGRESSED (r12 occupancy cliff); BK=128 rejected (m132).
// MFMA frag maps (16x16x32): A/B lane l -> row l&15, k (l>>4)*8+j;
//                            C/D lane l -> col l&15, row (l>>4)*4+r.
// EPI: 0 = bf16 out (+bias), 2 = bf16 gelu(+bias),
//      3 = bf16 out (+bias + bf16 res)  [pre-LN sum],
//      4 = qkv: cols<1024 like EPI0; V-col blocks (rowB0>=1024, uniform)
//          transpose acc through padded LDS and store vt (r16, verified).
// ---------------------------------------------------------------------------
template<int BM, int BN, int WGM, int WGN, int EPI>
__global__ __launch_bounds__(256) void gemm_bf16(
    const unsigned short* __restrict__ A, int lda, long aHi, long aLo,
    const unsigned short* __restrict__ B, int ldb, long bHi, long bLo,
    void* __restrict__ Cout, int ldc, long cHi, long cLo,
    const float* __restrict__ bias,
    const unsigned short* __restrict__ resb, int ldr,
    int K, unsigned short* __restrict__ vtout)
{
    constexpr int BK = 64;
    constexpr int FM = BM / (WGM * 16);
    constexpr int FN = BN / (WGN * 16);
    constexpr int CHA = BM / 8;         // 1KB chunks (8 rows x 128B) in A tile
    constexpr int CHB = BN / 8;
    extern __shared__ unsigned short glds[];
    unsigned short* As = glds;                  // [2][BM*BK]
    unsigned short* Bs = glds + 2 * BM * BK;    // [2][BN*BK]

    const int z  = blockIdx.z;
    const int zh = z >> 3, zl = z & 7;
    A += zh * aHi + zl * aLo;
    B += zh * bHi + zl * bLo;
    const long coff = zh * cHi + zl * cLo;

    const int tid  = threadIdx.x;
    const int lane = tid & 63;
    const int w    = tid >> 6;
    const int wr   = w / WGN, wc = w % WGN;
    const long rowA0 = (long)blockIdx.x * BM;
    const long rowB0 = (long)blockIdx.y * BN;

    f32x4 acc[FM][FN];
    #pragma unroll
    for (int m = 0; m < FM; m++)
        #pragma unroll
        for (int n = 0; n < FN; n++)
            #pragma unroll
            for (int r = 0; r < 4; r++) acc[m][n][r] = 0.f;

    const int lr   = lane & 15;
    const int crow = lane >> 3;                        // row within 8-row chunk
    const int ccol = ((lane & 7) ^ crow) * 8;          // pre-swizzled src col

    auto stage = [&](int bf, int k0) {
        #pragma unroll
        for (int c0 = 0; c0 < CHA / 4; c0++) {
            const int c = c0 * 4 + w;
            gload16(&A[(rowA0 + c * 8 + crow) * (long)lda + k0 + ccol],
                    &As[bf * BM * BK + c * 512]);
        }
        #pragma unroll
        for (int c0 = 0; c0 < CHB / 4; c0++) {
            const int c = c0 * 4 + w;
            gload16(&B[(rowB0 + c * 8 + crow) * (long)ldb + k0 + ccol],
                    &Bs[bf * BN * BK + c * 512]);
        }
    };

    stage(0, 0);
    int cur = 0;
    for (int k0 = 0; k0 < K; k0 += BK) {
        __syncthreads();   // tile t landed (vmcnt0); prev readers of cur^1 done
        if (k0 + BK < K) stage(cur ^ 1, k0 + BK);   // prefetch next tile

        #pragma unroll
        for (int kh = 0; kh < 2; kh++) {
            bf16x8 af[FM], bfr[FN];
            const int sl = ((kh * 4 + (lane >> 4)) ^ (lr & 7)) * 8;
            #pragma unroll
            for (int m = 0; m < FM; m++)
                af[m] = *(const bf16x8*)
                    &As[cur * BM * BK + (wr * FM * 16 + m * 16 + lr) * BK + sl];
            #pragma unroll
            for (int n = 0; n < FN; n++)
                bfr[n] = *(const bf16x8*)
                    &Bs[cur * BN * BK + (wc * FN * 16 + n * 16 + lr) * BK + sl];
            #pragma unroll
            for (int m = 0; m < FM; m++)
                #pragma unroll
                for (int n = 0; n < FN; n++)
                    acc[m][n] = __builtin_amdgcn_mfma_f32_16x16x32_bf16(
                        af[m], bfr[n], acc[m][n], 0, 0, 0);
        }
        cur ^= 1;
    }

    const int rg = (lane >> 4) * 4;
    if constexpr (EPI == 4) {
        if (rowB0 >= 2 * D_) {
            // ---- V-col block: acc -> LDS (padded) -> transposed vt store ----
            unsigned short* T = glds;          // [128 rows l][stride 132] bf16
            __syncthreads();                   // all K-loop LDS reads done
            #pragma unroll
            for (int m = 0; m < FM; m++)
                #pragma unroll
                for (int n = 0; n < FN; n++) {
                    const int lcol = wc * FN * 16 + n * 16 + lr;     // 0..127
                    const float bv = bias[(int)rowB0 + lcol];
                    #pragma unroll
                    for (int r = 0; r < 4; r++) {
                        const int lrow = wr * FM * 16 + m * 16 + rg + r;
                        T[lrow * 132 + lcol] = f2bf(acc[m][n][r] + bv);
                    }
                }
            __syncthreads();
            const int bb = (int)(rowA0 >> 9);          // batch (BM=128 | 512)
            const int l0 = (int)(rowA0 & 511);         // l-tile base (128-al)
            const int vcBase = (int)(rowB0 - 2 * D_);  // 0..384 step 128
            for (int c = tid; c < 2048; c += 256) {
                const int vc    = c & 127;             // local v col
                const int ch    = c >> 7;              // 0..15 l-chunk of 8
                const int lt2   = ch >> 3;             // 64-l tile (0/1)
                const int gslot = ch & 7;
                const int gvc = vcBase + vc;
                const int hd = gvc >> 6, d = gvc & 63;
                bf16x8 o;
                #pragma unroll
                for (int j = 0; j < 8; j++)
                    o[j] = (short)T[(lt2 * 64 + gslot * 8 + j) * 132 + vc];
                *(bf16x8*)&vtout[(long)(bb * 8 + hd) * (DH_ * L_)
                                 + (long)d * 512 + l0 + lt2 * 64
                                 + ((gslot ^ (d & 7)) * 8)] = o;
            }
            return;
        }
        // Q,K cols: plain bf16 store to qkv
        #pragma unroll
        for (int m = 0; m < FM; m++)
            #pragma unroll
            for (int n = 0; n < FN; n++) {
                const int col = (int)rowB0 + wc * FN * 16 + n * 16 + lr;
                const float bv = bias[col];
                #pragma unroll
                for (int r = 0; r < 4; r++) {
                    const long row = rowA0 + wr * FM * 16 + m * 16 + rg + r;
                    ((unsigned short*)Cout)[row * ldc + col] =
                        f2bf(acc[m][n][r] + bv);
                }
            }
        return;
    }

    #pragma unroll
    for (int m = 0; m < FM; m++) {
        #pragma unroll
        for (int n = 0; n < FN; n++) {
            const int col = (int)rowB0 + wc * FN * 16 + n * 16 + lr;
            const float bv = bias ? bias[col] : 0.f;
            #pragma unroll
            for (int r = 0; r < 4; r++) {
                const long row = rowA0 + wr * FM * 16 + m * 16 + rg + r;
                float v = acc[m][n][r] + bv;
                const long o = coff + row * ldc + col;
                if constexpr (EPI == 0) {
                    ((unsigned short*)Cout)[o] = f2bf(v);
                } else if constexpr (EPI == 3) {
                    ((unsigned short*)Cout)[o] =
                        f2bf(v + bf2f(resb[row * ldr + col]));
                } else {
                    float g = 0.5f * v * (1.f + erff(v * 0.70710678118f));
                    ((unsigned short*)Cout)[o] = f2bf(g);
                }
            }
        }
    }
}

// ---------------------------------------------------------------------------
// Fused attention v3 (REVERTED from v4 — r17 post-mortem: v4's 3 extra
// barriers + divergent 2-of-4-wave P-write cost more than its ds_read
// savings; QK^T reads were already TLP-hidden at 2 blocks/CU).
// One block = 64 q-rows of one (b,h). QK^T as mfma(K,Q): lane holds
// S[k][q] with q = w*16+(lane&15) fixed -> softmax is in-lane tree + 2 shfl.
// P~ = exp(S-max), un-normalized (<=1, bf16-safe); rinv folded into O store.
// PV per 256-key half: P~ packed 4-wide -> ds_write_b64 into swizzled Ps
// (aliases Ks lower half; per-wave-disjoint rows), V^T staged via LINEAR
// gload16 from pre-swizzled vt into Vb (aliases Ks upper half).
// O^T = mfma(V^T, P~). LDS 72KB -> 2 blocks/CU. Grid 1-D, head = bid&127.
// ---------------------------------------------------------------------------
__global__ __launch_bounds__(256) void attn_kernel(
    const unsigned short* __restrict__ qkv,   // (B, L, 3D) bf16 (Q,K valid)
    const unsigned short* __restrict__ vt,    // (B*H, 64, 512) bf16 V^T, swz
    unsigned short* __restrict__ attno)       // (B, L, D) bf16
{
    extern __shared__ unsigned short lds[];   // 36864 shorts = 72KB
    unsigned short* Qs = lds;                 // [64][64]   swz ^row&7
    unsigned short* Ks = lds + 4096;          // [512][64]  swz ^row&7
    unsigned short* Ps = lds + 4096;          // [64 q][256] swz ^(q&7) (alias)
    unsigned short* Vb = lds + 20480;         // [64 d][256] swz ^(d&7) (alias)

    const int bid = blockIdx.x;
    const int z   = bid & 127;                // b*8+h
    const int qb  = bid >> 7;
    const int b = z >> 3, hh = z & 7;
    const unsigned short* Q  = qkv + (long)b * (L_ * 3 * D_) + hh * DH_;
    const unsigned short* Kp = Q + D_;
    const int row0 = qb * 64;

    const int tid = threadIdx.x, lane = tid & 63, w = tid >> 6;
    const int lr = lane & 15, lg = lane >> 4;

    // ---- stage Q (8 chunks) + K (64 chunks); 1KB chunk = 8 rows x 128B ----
    const int srow = lane >> 3;
    const int scol = ((lane & 7) ^ (srow & 7)) * 8;   // pre-swizzled src col
    #pragma unroll
    for (int c = 0; c < 2; c++)
        gload16(&Q[(long)(row0 + (w * 2 + c) * 8 + srow) * (3 * D_) + scol],
                &Qs[(w * 2 + c) * 512]);
    #pragma unroll
    for (int c = 0; c < 16; c++)
        gload16(&Kp[(long)((c * 4 + w) * 8 + srow) * (3 * D_) + scol],
                &Ks[(c * 4 + w) * 512]);
    __syncthreads();

    // ---- QK^T swapped: acc[n][r] = S[k=n*16+lg*4+r][q=w*16+lr] ----
    f32x4 acc[32];
    #pragma unroll
    for (int n = 0; n < 32; n++)
        #pragma unroll
        for (int r = 0; r < 4; r++) acc[n][r] = 0.f;

    __builtin_amdgcn_s_setprio(1);
    #pragma unroll
    for (int ks = 0; ks < 2; ks++) {
        const int sl = ((ks * 4 + lg) ^ (lr & 7)) * 8;
        bf16x8 qf = *(const bf16x8*)&Qs[(w * 16 + lr) * 64 + sl];
        #pragma unroll
        for (int n = 0; n < 32; n++) {
            bf16x8 kf = *(const bf16x8*)&Ks[(n * 16 + lr) * 64 + sl];
            acc[n] = __builtin_amdgcn_mfma_f32_16x16x32_bf16(kf, qf, acc[n], 0, 0, 0);
        }
    }
    __builtin_amdgcn_s_setprio(0);

    // ---- lane-local softmax over the 128 k-values (+quartet shfl) ----
    constexpr float scale = 0.125f;           // 1/sqrt(64)
    float red[32];
    #pragma unroll
    for (int n = 0; n < 32; n++)
        red[n] = fmaxf(fmaxf(acc[n][0], acc[n][1]), fmaxf(acc[n][2], acc[n][3]));
    #pragma unroll
    for (int st = 16; st; st >>= 1)
        #pragma unroll
        for (int i = 0; i < 16; i++)
            if (i < st) red[i] = fmaxf(red[i], red[i + st]);
    float mx = red[0];
    mx = fmaxf(mx, __shfl_xor(mx, 16));
    mx = fmaxf(mx, __shfl_xor(mx, 32));
    const float ms = mx * scale;
    #pragma unroll
    for (int n = 0; n < 32; n++) {
        float e0 = __expf(acc[n][0] * scale - ms);
        float e1 = __expf(acc[n][1] * scale - ms);
        float e2 = __expf(acc[n][2] * scale - ms);
        float e3 = __expf(acc[n][3] * scale - ms);
        acc[n][0] = e0; acc[n][1] = e1; acc[n][2] = e2; acc[n][3] = e3;
        red[n] = (e0 + e1) + (e2 + e3);
    }
    #pragma unroll
    for (int st = 16; st; st >>= 1)
        #pragma unroll
        for (int i = 0; i < 16; i++)
            if (i < st) red[i] += red[i + st];
    float s = red[0];
    s += __shfl_xor(s, 16);
    s += __shfl_xor(s, 32);
    const float rinv = 1.f / s;

    __syncthreads();   // ALL waves done reading Ks before Ps/Vb overwrite

    // ---- PV in two 256-key halves ----
    const long vbase = (long)z * (DH_ * L_);
    const int vrow2 = lane >> 5;              // chunk = 2 rows x 512B
    const int vs    = lane & 31;
    const int q     = w * 16 + lr;
    f32x4 accO[4];
    #pragma unroll
    for (int dt = 0; dt < 4; dt++)
        #pragma unroll
        for (int r = 0; r < 4; r++) accO[dt][r] = 0.f;

    #pragma unroll
    for (int hf = 0; hf < 2; hf++) {
        if (hf) __syncthreads();   // all waves done reading Vb half0
        // issue V-half stage first (linear copy; swizzle pre-baked in vt)
        #pragma unroll
        for (int c = 0; c < 8; c++) {
            const int ch = c * 4 + w;
            const int dloc = ch * 2 + vrow2;
            gload16(&vt[vbase + (long)dloc * 512 + hf * 256 + vs * 8],
                    &Vb[ch * 512]);
        }
        // write P~ half: 16 x ds_write_b64 into swizzled Ps rows (own rows)
        #pragma unroll
        for (int n = 0; n < 16; n++) {
            const int slot = (n * 2 + (lg >> 1)) ^ (lr & 7);
            unsigned long long pk = pack4(acc[hf * 16 + n][0], acc[hf * 16 + n][1],
                                          acc[hf * 16 + n][2], acc[hf * 16 + n][3]);
            *(unsigned long long*)&Ps[q * 256 + slot * 8 + (lg & 1) * 4] = pk;
        }
        __syncthreads();           // Vb landed (vmcnt0) + Ps visible
        __builtin_amdgcn_s_setprio(1);
        #pragma unroll
        for (int kstep = 0; kstep < 8; kstep++) {
            const int sl = ((kstep * 4 + lg) ^ (lr & 7)) * 8;
            bf16x8 pf = *(const bf16x8*)&Ps[q * 256 + sl];
            #pragma unroll
            for (int dt = 0; dt < 4; dt++) {
                bf16x8 vf = *(const bf16x8*)&Vb[(dt * 16 + lr) * 256 + sl];
                accO[dt] = __builtin_amdgcn_mfma_f32_16x16x32_bf16(vf, pf, accO[dt], 0, 0, 0);
            }
        }
        __builtin_amdgcn_s_setprio(0);
    }

    // ---- store O (rinv folded): d = dt*16 + lg*4 + r, packed 8B ----
    unsigned short* op = attno + (long)(b * L_ + row0 + q) * D_ + hh * DH_;
    #pragma unroll
    for (int dt = 0; dt < 4; dt++) {
        unsigned long long pk = pack4(accO[dt][0] * rinv, accO[dt][1] * rinv,
                                      accO[dt][2] * rinv, accO[dt][3] * rinv);
        *(unsigned long long*)&op[dt * 16 + lg * 4] = pk;
    }
}

// ---------------------------------------------------------------------------
// All four weight tensors -> bf16 arena in one launch (regions contiguous).
__global__ __launch_bounds__(256) void cvtall_kernel(
    const float* __restrict__ s0, const float* __restrict__ s1,
    const float* __restrict__ s2, const float* __restrict__ s3,
    unsigned short* __restrict__ dst)
{
    const long n0 = 786432, n1 = 262144, n2 = 1048576;   // float4 counts
    long i4 = (long)blockIdx.x * 256 + threadIdx.x;
    const float* s; long off;
    if (i4 < n0)                { s = s0; off = 0; }
    else if (i4 < n0 + n1)      { s = s1; off = n0; }
    else if (i4 < n0 + n1 + n2) { s = s2; off = n0 + n1; }
    else                        { s = s3; off = n0 + n1 + n2; }
    float4 v = ((const float4*)s)[i4 - off];
    *(unsigned long long*)&dst[i4 * 4] = pack4(v.x, v.y, v.z, v.w);
}

__global__ __launch_bounds__(256) void embed_kernel(
    const int* __restrict__ x, const float* __restrict__ emb,
    const float* __restrict__ pos, unsigned short* __restrict__ hb)
{
    const long row = blockIdx.x;            // 0..B*L-1
    const int tok = x[row];
    const int l = (int)(row & (L_ - 1));
    const int d0 = threadIdx.x * 2;
    float2 e = *(const float2*)&emb[(long)tok * D_ + d0];
    float2 p = *(const float2*)&pos[(long)l * D_ + d0];
    float a0 = e.x + p.x, a1 = e.y + p.y;
    unsigned int pk = (unsigned int)f2bf(a0) | ((unsigned int)f2bf(a1) << 16);
    *(unsigned int*)&hb[row * D_ + d0] = pk;
}

// LN over bf16 pre-LN sums (tbuf), writes bf16 hb only (residual stream).
__global__ __launch_bounds__(256) void ln_kernel(
    const unsigned short* __restrict__ t, const float* __restrict__ g,
    const float* __restrict__ bb, unsigned short* __restrict__ hb)
{
    const int lane = threadIdx.x & 63;
    const long row = (long)blockIdx.x * 4 + (threadIdx.x >> 6);
    const unsigned short* x = t + row * D_;
    float v[8];
    bf16x8 d = *(const bf16x8*)&x[lane * 8];
    #pragma unroll
    for (int j = 0; j < 8; j++) v[j] = bf2f((unsigned short)d[j]);
    float s = 0.f;
    #pragma unroll
    for (int j = 0; j < 8; j++) s += v[j];
    #pragma unroll
    for (int o = 32; o; o >>= 1) s += __shfl_xor(s, o);
    const float m = s * (1.f / D_);
    float q = 0.f;
    #pragma unroll
    for (int j = 0; j < 8; j++) { float dd = v[j] - m; q += dd * dd; }
    #pragma unroll
    for (int o = 32; o; o >>= 1) q += __shfl_xor(q, o);
    const float rr = rsqrtf(q * (1.f / D_) + 1e-5f);
    bf16x8 ob;
    #pragma unroll
    for (int j = 0; j < 8; j++) {
        int dd = lane * 8 + j;
        ob[j] = (short)f2bf((v[j] - m) * rr * g[dd] + bb[dd]);
    }
    *(bf16x8*)&hb[row * D_ + lane * 8] = ob;
}

__global__ __launch_bounds__(512) void ctxmean_kernel(
    const unsigned short* __restrict__ hb, float* __restrict__ ctx)
{
    const int b = blockIdx.x, seg = blockIdx.y;
    const int d = threadIdx.x;
    float s = 0.f;
    #pragma unroll 4
    for (int l = seg * 64; l < seg * 64 + 64; l++)
        s += bf2f(hb[((long)b * L_ + l) * D_ + d]);
    atomicAdd(&ctx[b * D_ + d], s * (1.f / L_));
}

__global__ __launch_bounds__(256) void zero_kernel(float* __restrict__ p, long n)
{
    long i = (long)blockIdx.x * 256 + threadIdx.x;
    if (i < n) p[i] = 0.f;
}

// scatter-zero: reset counts only at positions hist will increment.
// duplicate-token write races all write 0.0f -> benign, deterministic.
__global__ __launch_bounds__(256) void zscat_kernel(
    const int* __restrict__ x, float* __restrict__ counts)
{
    const int i = blockIdx.x * 256 + threadIdx.x;
    if (i >= B_ * L_) return;
    const int tok = x[i];
    if (tok != 0) counts[(long)(i >> 9) * V_ + tok] = 0.f;
}

__global__ __launch_bounds__(256) void hist_kernel(
    const int* __restrict__ x, float* __restrict__ counts)
{
    const int i = blockIdx.x * 256 + threadIdx.x;
    if (i >= B_ * L_) return;
    const int tok = x[i];
    if (tok != 0) atomicAdd(&counts[(long)(i >> 9) * V_ + tok], 1.0f);
}

// Σ_v c_v = #nonpad tokens; Σ_v c_v² = Σ_{t,nonpad} c[x_t]  (512 gathers/b
// instead of a 50257-scan; single block per b, no atomics, exact integers).
__global__ __launch_bounds__(512) void cstats_kernel(
    const int* __restrict__ x, const float* __restrict__ counts,
    float* __restrict__ statsraw)
{
    const int b = blockIdx.x, t = threadIdx.x;
    const int tok = x[b * L_ + t];
    float s1 = 0.f, s2 = 0.f;
    if (tok != 0) { s1 = 1.f; s2 = counts[(long)b * V_ + tok]; }
    #pragma unroll
    for (int o = 32; o; o >>= 1) { s1 += __shfl_xor(s1, o); s2 += __shfl_xor(s2, o); }
    __shared__ float r1[8], r2[8];
    if ((t & 63) == 0) { r1[t >> 6] = s1; r2[t >> 6] = s2; }
    __syncthreads();
    if (t == 0) {
        float t1 = 0.f, t2 = 0.f;
        #pragma unroll
        for (int i = 0; i < 8; i++) { t1 += r1[i]; t2 += r2[i]; }
        statsraw[b * 2] = t1;
        statsraw[b * 2 + 1] = t2;
    }
}

// Pure scaled transpose: WcT_g[v][cd] = Wc[cd][v] * g[v]  (no atomics)
__global__ __launch_bounds__(256) void wct_kernel(
    const float* __restrict__ Wc, const float* __restrict__ g,
    float* __restrict__ WcT)
{
    __shared__ float tile[64][65];
    __shared__ float gs[64];
    const int v0 = blockIdx.x * 64;
    const int t = threadIdx.x;
    if (t < 64) gs[t] = (v0 + t < V_) ? g[v0 + t] : 0.f;
    const int vv = t & 63;
    const int vg = v0 + vv;
    #pragma unroll
    for (int r = 0; r < 16; r++) {
        int cd = r * 4 + (t >> 6);
        tile[cd][vv] = (vg < V_) ? Wc[(long)cd * V_ + vg] : 0.f;
    }
    __syncthreads();
    #pragma unroll
    for (int r = 0; r < 16; r++) {
        int v2 = r * 4 + (t >> 6);
        int cd = t & 63;
        if (v0 + v2 < V_)
            WcT[(long)(v0 + v2) * 64 + cd] = tile[cd][v2] * gs[v2];
    }
}

// sgb[cd] = {Σ_v Wc[cd][v]·g[v], Σ_v Wc[cd][v]·β[v]} — 4 chunks/cd, 2 atomics/blk
__global__ __launch_bounds__(256) void sgbred_kernel(
    const float* __restrict__ Wc, const float* __restrict__ g,
    const float* __restrict__ bb, float* __restrict__ sgb)
{
    const int cd = blockIdx.x >> 2, chunk = blockIdx.x & 3;
    const int n0 = chunk * 12565;
    const int n1 = min(n0 + 12565, V_);
    float s1 = 0.f, s2 = 0.f;
    for (int v = n0 + threadIdx.x; v < n1; v += 256) {
        float wv = Wc[(long)cd * V_ + v];
        s1 += wv * g[v];
        s2 += wv * bb[v];
    }
    #pragma unroll
    for (int o = 32; o; o >>= 1) { s1 += __shfl_xor(s1, o); s2 += __shfl_xor(s2, o); }
    __shared__ float r1[4], r2[4];
    if ((threadIdx.x & 63) == 0) { r1[threadIdx.x >> 6] = s1; r2[threadIdx.x >> 6] = s2; }
    __syncthreads();
    if (threadIdx.x == 0) {
        atomicAdd(&sgb[cd * 2],     r1[0] + r1[1] + r1[2] + r1[3]);
        atomicAdd(&sgb[cd * 2 + 1], r2[0] + r2[1] + r2[2] + r2[3]);
    }
}

// dot[b][cd] = Σ_t!=pad WcT_g[x_bt][cd]  (contiguous 256B rows per token)
__global__ __launch_bounds__(256) void cgather_kernel(
    const int* __restrict__ x, const float* __restrict__ WcT,
    float* __restrict__ dot)
{
    const int b = blockIdx.x, seg = blockIdx.y;
    const int wv = threadIdx.x >> 6, lane = threadIdx.x & 63;
    float s = 0.f;
    #pragma unroll
    for (int i = 0; i < 16; i++) {
        int tok = x[b * L_ + seg * 64 + wv * 16 + i];
        if (tok != 0) s += WcT[(long)tok * 64 + lane];
    }
    atomicAdd(&dot[b * 64 + lane], s);
}

__global__ void cfinal_kernel(
    const float* __restrict__ dot, const float* __restrict__ statsraw,
    const float* __restrict__ sgb, const float* __restrict__ bc,
    float* __restrict__ cf)
{
    const int b = blockIdx.x, cd = threadIdx.x;
    const float s1 = statsraw[b * 2], s2 = statsraw[b * 2 + 1];
    const float m = s1 * (1.f / V_);
    const float r = rsqrtf(s2 * (1.f / V_) - m * m + 1e-5f);
    float v = r * (dot[b * 64 + cd] - m * sgb[cd * 2]) + sgb[cd * 2 + 1] + bc[cd];
    cf[b * CD_ + cd] = fmaxf(v, 0.f);
}

__global__ __launch_bounds__(256) void final_kernel(
    const float* __restrict__ ctx, const float* __restrict__ cf,
    const float* __restrict__ Wh, const float* __restrict__ bh,
    float* __restrict__ out)
{
    const int p = threadIdx.x;
    if (p >= B_ * C_) return;
    const int b = p / C_, c = p % C_;
    float s = bh[c];
    const float* wrow = Wh + (long)c * (D_ + CD_);
    for (int d = 0; d < D_; d++) s += ctx[b * D_ + d] * wrow[d];
    for (int j = 0; j < CD_; j++) s += cf[b * CD_ + j] * wrow[D_ + j];
    out[p] = s;
}

// ---------------------------------------------------------------------------
extern "C" void kernel_launch(void* const* d_in, const int* in_sizes, int n_in,
                              void* d_out, int out_size, void* d_ws, size_t ws_size,
                              hipStream_t stream)
{
    const int*   x      = (const int*)  d_in[0];
    const float* embedw = (const float*)d_in[1];
    const float* pos    = (const float*)d_in[2];
    const float* Wqkv   = (const float*)d_in[3];
    const float* bqkv   = (const float*)d_in[4];
    const float* Wo     = (const float*)d_in[5];
    const float* bo     = (const float*)d_in[6];
    const float* ln1g   = (const float*)d_in[7];
    const float* ln1b   = (const float*)d_in[8];
    const float* W1     = (const float*)d_in[9];
    const float* b1     = (const float*)d_in[10];
    const float* W2     = (const float*)d_in[11];
    const float* b2     = (const float*)d_in[12];
    const float* ln2g   = (const float*)d_in[13];
    const float* ln2b   = (const float*)d_in[14];
    const float* cgv    = (const float*)d_in[15];
    const float* cbv    = (const float*)d_in[16];
    const float* Wc     = (const float*)d_in[17];
    const float* bc     = (const float*)d_in[18];
    const float* Wh     = (const float*)d_in[19];
    const float* bh     = (const float*)d_in[20];
    float* out = (float*)d_out;

    char* ws = (char*)d_ws;
    size_t off = 0;
    auto alloc = [&](size_t bytes) -> void* {
        void* p = ws + off;
        off += (bytes + 255) & ~(size_t)255;
        return p;
    };
    unsigned short* hb    = (unsigned short*)alloc((size_t)B_ * L_ * D_ * 2);
    unsigned short* qkv   = (unsigned short*)alloc((size_t)B_ * L_ * 3 * D_ * 2);
    unsigned short* vt    = (unsigned short*)alloc((size_t)B_ * H_ * DH_ * L_ * 2);
    unsigned short* ff1   = (unsigned short*)alloc((size_t)B_ * L_ * 4 * D_ * 2);
    unsigned short* attno = (unsigned short*)alloc((size_t)B_ * L_ * D_ * 2);
    unsigned short* tbuf  = (unsigned short*)alloc((size_t)B_ * L_ * D_ * 2);
    unsigned short* wqb   = (unsigned short*)alloc((size_t)NL_ * 3 * D_ * D_ * 2);
    unsigned short* wob   = (unsigned short*)alloc((size_t)NL_ * D_ * D_ * 2);
    unsigned short* w1b   = (unsigned short*)alloc((size_t)NL_ * 4 * D_ * D_ * 2);
    unsigned short* w2b   = (unsigned short*)alloc((size_t)NL_ * 4 * D_ * D_ * 2);
    float*          counts= (float*)alloc((size_t)B_ * V_ * 4);
    float*          statsraw = (float*)alloc(B_ * 2 * 4);
    float*          sgb   = (float*)alloc(CD_ * 2 * 4);
    float*          dot   = (float*)alloc(B_ * CD_ * 4);
    float*          ctx   = (float*)alloc(B_ * D_ * 4);
    float*          cf    = (float*)alloc(B_ * CD_ * 4);
    // WcT_g (Vpad x 64 f32, 12.9MB) aliases qkv: only used after encoder loop.
    float*          WcT   = (float*)qkv;

    // all weights -> bf16 arena (wqb..w2b contiguous), one launch
    cvtall_kernel<<<12288, 256, 0, stream>>>(Wqkv, Wo, W1, W2, wqb);

    embed_kernel<<<B_*L_, 256, 0, stream>>>(x, embedw, pos, hb);

    // dynamic LDS: (BM+BN)*BK*4 bytes (2 bufs x (A+B) x BK x 2B)
    const int lds_128 = (128 + 128) * 64 * 4;   // 65536
    const int lds_64  = (64 + 128) * 64 * 4;    // 49152

    for (int i = 0; i < NL_; i++) {
        // qkv = h @ Wqkv^T + bqkv  (M=8192,N=1536,K=512); V cols -> vt via
        // LDS-transposed epilogue (vtrans kernel deleted)
        gemm_bf16<128,128,2,2,4><<<dim3(64,12,1),256,lds_128,stream>>>(
            hb, 512, 0, 0,
            wqb + (size_t)i*786432, 512, 0, 0,
            qkv, 1536, 0, 0,
            bqkv + i*1536, nullptr, 0, 512, vt);
        // fused O = softmax(QK^T/8) @ V  (P never leaves the CU)
        attn_kernel<<<1024, 256, 73728, stream>>>(qkv, vt, attno);
        // t = bf16(hb + O @ Wo^T + bo)   (M=8192, N=512, K=512), 512 blocks
        gemm_bf16<64,128,1,4,3><<<dim3(128,4,1),256,lds_64,stream>>>(
            attno, 512, 0, 0,
            wob + (size_t)i*262144, 512, 0, 0,
            tbuf, 512, 0, 0,
            bo + i*512, hb, 512, 512, nullptr);
        ln_kernel<<<2048,256,0,stream>>>(tbuf, ln1g + i*512, ln1b + i*512, hb);
        // ff1 = gelu(h @ W1^T + b1)      (M=8192, N=2048, K=512) -> bf16
        gemm_bf16<128,128,2,2,2><<<dim3(64,16,1),256,lds_128,stream>>>(
            hb, 512, 0, 0,
            w1b + (size_t)i*1048576, 512, 0, 0,
            ff1, 2048, 0, 0,
            b1 + i*2048, nullptr, 0, 512, nullptr);
        // t = bf16(hb + ff1 @ W2^T + b2) (M=8192, N=512, K=2048), 512 blocks
        gemm_bf16<64,128,1,4,3><<<dim3(128,4,1),256,lds_64,stream>>>(
            ff1, 2048, 0, 0,
            w2b + (size_t)i*1048576, 2048, 0, 0,
            tbuf, 512, 0, 0,
            b2 + i*512, hb, 512, 2048, nullptr);
        ln_kernel<<<2048,256,0,stream>>>(tbuf, ln2g + i*512, ln2b + i*512, hb);
    }

    // ---- heads (count path runs after encoder; WcT aliases qkv) ----
    // zero only the atomic-target region (statsraw..cf, ~41KB); counts is
    // scatter-zeroed at exactly the positions hist touches.
    {
        long span = (((char*)cf + ((B_*CD_*4 + 255) & ~255)) - (char*)statsraw) / 4;
        zero_kernel<<<(span + 255)/256, 256, 0, stream>>>(statsraw, span);
    }
    zscat_kernel<<<(B_*L_ + 255)/256, 256, 0, stream>>>(x, counts);
    ctxmean_kernel<<<dim3(B_,8),512,0,stream>>>(hb, ctx);
    hist_kernel<<<(B_*L_ + 255)/256, 256, 0, stream>>>(x, counts);
    cstats_kernel<<<B_,512,0,stream>>>(x, counts, statsraw);
    wct_kernel<<<(V_ + 63)/64, 256, 0, stream>>>(Wc, cgv, WcT);
    sgbred_kernel<<<256,256,0,stream>>>(Wc, cgv, cbv, sgb);
    cgather_kernel<<<dim3(B_,8),256,0,stream>>>(x, WcT, dot);
    cfinal_kernel<<<B_,64,0,stream>>>(dot, statsraw, sgb, bc, cf);
    final_kernel<<<1,256,0,stream>>>(ctx, cf, Wh, bh, out);
}